// Round 2
// baseline (684.837 us; speedup 1.0000x reference)
//
#include <hip/hip_runtime.h>
#include <hip/hip_fp16.h>
#include <stdint.h>

typedef __attribute__((ext_vector_type(8))) short short8;
typedef __attribute__((ext_vector_type(16))) float f32x16;
typedef unsigned int u32;
typedef unsigned long long u64;

#define DEVI __device__ __forceinline__

// pack two f32 -> two f16 in one u32 (lo=a, hi=b); compiler emits v_cvt_pkrtz
DEVI u32 pkh(float a, float b){
  u32 la = (u32)__half_as_ushort(__float2half(a));
  u32 lb = (u32)__half_as_ushort(__float2half(b));
  return la | (lb << 16);
}

DEVI f32x16 zero16(){
  f32x16 z;
#pragma unroll
  for (int i = 0; i < 16; ++i) z[i] = 0.0f;
  return z;
}

// async global->LDS, 16B per lane, wave-uniform LDS base + lane*16
#define GLOAD16(gsrc, ldst) \
  __builtin_amdgcn_global_load_lds((const __attribute__((address_space(1))) u32*)(gsrc), \
                                   (__attribute__((address_space(3))) u32*)(ldst), 16, 0, 0)

#define TR_READ(dst, addr, IMM) \
  asm volatile("ds_read_b64_tr_b16 %0, %1 offset:" IMM : "=v"(dst) : "v"(addr))

// B=4 H=16 S=2048 D=128. grid=1024 (XCD-swizzled), 256 threads = 4 waves x 32 q rows.
// KVBLK=32, 64 tiles, double-buffered LDS, one __syncthreads per tile.
__global__ __launch_bounds__(256, 3)
void sdpa_fwd(const float* __restrict__ Qg, const float* __restrict__ Kg,
              const float* __restrict__ Vg, const int* __restrict__ Mg,
              float* __restrict__ Og)
{
  constexpr int S = 2048, D = 128;
  // K: f32, XOR-swizzled rows [32][512B], double buffered = 32 KB
  __shared__ __align__(16) char Kl[2*16384];
  // V: f16, tr-subtiled [kv/4][d/16][4][16], double buffered = 16 KB
  __shared__ __align__(16) char Vl[2*8192];
  __shared__ float Ml[2][32];

  const int tid  = threadIdx.x;
  const int lane = tid & 63;
  const int wv   = tid >> 6;
  const int h    = lane >> 5;
  const int r31  = lane & 31;
  const int r15  = lane & 15;
  const int b4   = (lane >> 4) & 1;

  // XCD swizzle: same-bh q-blocks co-located on one XCD, consecutive in time
  const int bi  = blockIdx.x;
  const int xcd = bi & 7, rr = bi >> 3;
  const int qb  = rr & 15, bhl = rr >> 4;
  const int bh  = xcd*8 + bhl;

  const float* Qh = Qg + (size_t)bh * S * D;
  const float* Kh = Kg + (size_t)bh * S * D;
  const float* Vh = Vg + (size_t)bh * S * D;
  const int*   Mh = Mg + (size_t)bh * S;
  float*       Oh = Og + (size_t)bh * S * D;

  const int q0 = qb*128 + wv*32 + r31;

  // ---- Q fragments (f16 B-operand: lane holds Q[q0][df*16 + 8h + j]) ----
  short8 qs[8];
#pragma unroll
  for (int df = 0; df < 8; ++df){
    const float* p0 = Qh + (size_t)q0 * D + df*16 + h*8;
    float4 a = *(const float4*)(p0);
    float4 b = *(const float4*)(p0 + 4);
    union { u32 u[4]; short8 s; } cv;
    cv.u[0] = pkh(a.x, a.y); cv.u[1] = pkh(a.z, a.w);
    cv.u[2] = pkh(b.x, b.y); cv.u[3] = pkh(b.z, b.w);
    qs[df] = cv.s;
  }

  // staging index helpers
  const int vrow = tid >> 5;   // 0..7
  const int vcol = tid & 31;   // float4 col

  // ---- prologue: stage tile 0 into buf 0 ----
  {
#pragma unroll
    for (int j = 0; j < 4; ++j){                       // K via global_load_lds
      int ii = wv*4 + j;
      int row = 2*ii + h;
      u32 uoff = (u32)(lane & 31) * 16u;
      u32 col  = uoff ^ ((u32)(row & 15) << 4);
      const char* src = (const char*)Kh + ((size_t)row << 9) + col;
      GLOAD16(src, Kl + ii*1024);
    }
    float4 vr[4];
#pragma unroll
    for (int p = 0; p < 4; ++p)
      vr[p] = *(const float4*)&Vh[((size_t)(vrow + 8*p) << 7) + vcol*4];
#pragma unroll
    for (int p = 0; p < 4; ++p){
      int row = vrow + 8*p;
      u32 a = pkh(vr[p].x, vr[p].y), b = pkh(vr[p].z, vr[p].w);
      int E = ((row >> 2) << 10) + ((vcol >> 2) << 7) + ((row & 3) << 5) + ((vcol & 3) << 3);
      *(u64*)(Vl + E) = ((u64)b << 32) | a;
    }
    if (tid >= 224) Ml[0][tid-224] = (Mh[tid-224] != 0) ? 1.0f : 0.0f;
  }
  __syncthreads();

  f32x16 accO[4];
#pragma unroll
  for (int dn = 0; dn < 4; ++dn) accO[dn] = zero16();
  float mrun = -INFINITY, lrun = 0.0f;

  const u32 vbase = (u32)(size_t)(&Vl[0]) + (u32)(h*2048 + b4*128 + r15*8);

  for (int t = 0; t < 64; ++t){
    const int cur = t & 1, nb = cur ^ 1;
    const int kv0n = (t+1) * 32;
    float4 vr[4];
    float mreg = 1.0f;

    // ---- (a,b) issue next-tile loads (fly under the whole compute phase) ----
    if (t < 63){
#pragma unroll
      for (int j = 0; j < 4; ++j){
        int ii = wv*4 + j;
        int row = 2*ii + h;
        u32 uoff = (u32)(lane & 31) * 16u;
        u32 col  = uoff ^ ((u32)(row & 15) << 4);
        const char* src = (const char*)Kh + ((size_t)(kv0n + row) << 9) + col;
        GLOAD16(src, Kl + nb*16384 + ii*1024);
      }
#pragma unroll
      for (int p = 0; p < 4; ++p)
        vr[p] = *(const float4*)&Vh[((size_t)(kv0n + vrow + 8*p) << 7) + vcol*4];
      if (tid >= 224) mreg = (Mh[kv0n + tid-224] != 0) ? 1.0f : 0.0f;
    }

    // ---- QK^T (swapped): S^T[kv][q] = K_tile * Q^T, f32 K frags cvt'd on read ----
    f32x16 sa = zero16();
    const char* Kb = Kl + cur*16384;
    const u32 sw = ((u32)(r31 & 15)) << 4;
    __builtin_amdgcn_s_setprio(1);
#pragma unroll
    for (int df = 0; df < 8; ++df){
      u32 c0 = (u32)(df*64 + h*32);
      float4 ka = *(const float4*)(Kb + r31*512 + (c0 ^ sw));
      float4 kb = *(const float4*)(Kb + r31*512 + ((c0 + 16) ^ sw));
      union { u32 u[4]; short8 s; } cv;
      cv.u[0] = pkh(ka.x, ka.y); cv.u[1] = pkh(ka.z, ka.w);
      cv.u[2] = pkh(kb.x, kb.y); cv.u[3] = pkh(kb.z, kb.w);
      sa = __builtin_amdgcn_mfma_f32_32x32x16_f16(cv.s, qs[df], sa, 0, 0, 0);
    }
    __builtin_amdgcn_s_setprio(0);

    // ---- online softmax (lane owns q col = r31; kv rows split across h) ----
    float pmax = sa[0];
#pragma unroll
    for (int i = 1; i < 16; ++i) pmax = fmaxf(pmax, sa[i]);
    pmax = fmaxf(pmax, __shfl_xor(pmax, 32, 64));
    if (!__all(pmax - mrun <= 8.0f)){          // T13 defer-rescale
      float mnew = fmaxf(mrun, pmax);
      float sc = __expf(mrun - mnew);
      lrun *= sc;
#pragma unroll
      for (int dn = 0; dn < 4; ++dn)
#pragma unroll
        for (int i = 0; i < 16; ++i) accO[dn][i] *= sc;
      mrun = mnew;
    }
    float psum = 0.0f;
#pragma unroll
    for (int rb = 0; rb < 4; ++rb){
      float4 mv = *(const float4*)&Ml[cur][rb*8 + h*4];
      float mm[4] = {mv.x, mv.y, mv.z, mv.w};
#pragma unroll
      for (int i2 = 0; i2 < 4; ++i2){
        float e = __expf(sa[rb*4 + i2] - mrun) * mm[i2];
        sa[rb*4 + i2] = e;
        psum += e;
      }
    }
    psum += __shfl_xor(psum, 32, 64);
    lrun += psum;

    // ---- P fragments in-register (C-layout -> B-operand via xor-32 swap) ----
    short8 pf8[2];
#pragma unroll
    for (int kf = 0; kf < 2; ++kf){
      const int o = kf*8;
      u32 w0 = pkh(sa[o+0], sa[o+1]);
      u32 w1 = pkh(sa[o+2], sa[o+3]);
      u32 w2 = pkh(sa[o+4], sa[o+5]);
      u32 w3 = pkh(sa[o+6], sa[o+7]);
      u32 sw0 = __shfl_xor(w0, 32, 64);
      u32 sw1 = __shfl_xor(w1, 32, 64);
      u32 sw2 = __shfl_xor(w2, 32, 64);
      u32 sw3 = __shfl_xor(w3, 32, 64);
      union { u32 u[4]; short8 s; } cv;
      cv.u[0] = h ? sw2 : w0;
      cv.u[1] = h ? sw3 : w1;
      cv.u[2] = h ? w2  : sw0;
      cv.u[3] = h ? w3  : sw1;
      pf8[kf] = cv.s;
    }

    // ---- PV: issue all 16 tr reads, counted lgkmcnt ladder ----
    {
      const u32 vb = vbase + (u32)(cur * 8192);
      u64 t0,t1,t2,t3,t4,t5,t6,t7,t8,t9,t10,t11,t12,t13,t14,t15;
      TR_READ(t0,  vb, "0");    TR_READ(t1,  vb, "1024");
      TR_READ(t2,  vb, "4096"); TR_READ(t3,  vb, "5120");
      TR_READ(t4,  vb, "256");  TR_READ(t5,  vb, "1280");
      TR_READ(t6,  vb, "4352"); TR_READ(t7,  vb, "5376");
      TR_READ(t8,  vb, "512");  TR_READ(t9,  vb, "1536");
      TR_READ(t10, vb, "4608"); TR_READ(t11, vb, "5632");
      TR_READ(t12, vb, "768");  TR_READ(t13, vb, "1792");
      TR_READ(t14, vb, "4864"); TR_READ(t15, vb, "5888");

      __builtin_amdgcn_s_setprio(1);
      asm volatile("s_waitcnt lgkmcnt(12)" ::: "memory");
      __builtin_amdgcn_sched_barrier(0);
      { union { u64 q[2]; short8 s; } fa, fb;
        fa.q[0]=t0; fa.q[1]=t1; fb.q[0]=t2; fb.q[1]=t3;
        accO[0] = __builtin_amdgcn_mfma_f32_32x32x16_f16(fa.s, pf8[0], accO[0], 0,0,0);
        accO[0] = __builtin_amdgcn_mfma_f32_32x32x16_f16(fb.s, pf8[1], accO[0], 0,0,0); }
      asm volatile("s_waitcnt lgkmcnt(8)" ::: "memory");
      __builtin_amdgcn_sched_barrier(0);
      { union { u64 q[2]; short8 s; } fa, fb;
        fa.q[0]=t4; fa.q[1]=t5; fb.q[0]=t6; fb.q[1]=t7;
        accO[1] = __builtin_amdgcn_mfma_f32_32x32x16_f16(fa.s, pf8[0], accO[1], 0,0,0);
        accO[1] = __builtin_amdgcn_mfma_f32_32x32x16_f16(fb.s, pf8[1], accO[1], 0,0,0); }
      asm volatile("s_waitcnt lgkmcnt(4)" ::: "memory");
      __builtin_amdgcn_sched_barrier(0);
      { union { u64 q[2]; short8 s; } fa, fb;
        fa.q[0]=t8; fa.q[1]=t9; fb.q[0]=t10; fb.q[1]=t11;
        accO[2] = __builtin_amdgcn_mfma_f32_32x32x16_f16(fa.s, pf8[0], accO[2], 0,0,0);
        accO[2] = __builtin_amdgcn_mfma_f32_32x32x16_f16(fb.s, pf8[1], accO[2], 0,0,0); }
      asm volatile("s_waitcnt lgkmcnt(0)" ::: "memory");
      __builtin_amdgcn_sched_barrier(0);
      { union { u64 q[2]; short8 s; } fa, fb;
        fa.q[0]=t12; fa.q[1]=t13; fb.q[0]=t14; fb.q[1]=t15;
        accO[3] = __builtin_amdgcn_mfma_f32_32x32x16_f16(fa.s, pf8[0], accO[3], 0,0,0);
        accO[3] = __builtin_amdgcn_mfma_f32_32x32x16_f16(fb.s, pf8[1], accO[3], 0,0,0); }
      __builtin_amdgcn_s_setprio(0);
    }

    // ---- (d) finish next-tile V staging (loads have had the whole tile to land) ----
    if (t < 63){
#pragma unroll
      for (int p = 0; p < 4; ++p){
        int row = vrow + 8*p;
        u32 a = pkh(vr[p].x, vr[p].y), b = pkh(vr[p].z, vr[p].w);
        int E = ((row >> 2) << 10) + ((vcol >> 2) << 7) + ((row & 3) << 5) + ((vcol & 3) << 3);
        *(u64*)(Vl + nb*8192 + E) = ((u64)b << 32) | a;
      }
      if (tid >= 224) Ml[nb][tid-224] = mreg;
    }

    __syncthreads();   // drains vmcnt(0)+lgkmcnt(0): exactly the wait we need
  }

  // ---- epilogue: O[q][d] = accO^T / l ----
  const float inv = 1.0f / lrun;
  float* Orow = Oh + (size_t)q0 * D;
#pragma unroll
  for (int dn = 0; dn < 4; ++dn){
#pragma unroll
    for (int rb = 0; rb < 4; ++rb){
      float4 o4;
      o4.x = accO[dn][rb*4+0]*inv;
      o4.y = accO[dn][rb*4+1]*inv;
      o4.z = accO[dn][rb*4+2]*inv;
      o4.w = accO[dn][rb*4+3]*inv;
      *(float4*)&Orow[dn*32 + rb*8 + h*4] = o4;
    }
  }
}

extern "C" void kernel_launch(void* const* d_in, const int* in_sizes, int n_in,
                              void* d_out, int out_size, void* d_ws, size_t ws_size,
                              hipStream_t stream) {
  const float* q = (const float*)d_in[0];
  const float* k = (const float*)d_in[1];
  const float* v = (const float*)d_in[2];
  const int*   m = (const int*)d_in[3];
  float* out = (float*)d_out;
  sdpa_fwd<<<dim3(1024), dim3(256), 0, stream>>>(q, k, v, m, out);
}

// Round 3
// 247.541 us; speedup vs baseline: 2.7666x; 2.7666x over previous
//
#include <hip/hip_runtime.h>
#include <hip/hip_fp16.h>
#include <stdint.h>

typedef __attribute__((ext_vector_type(8))) short short8;
typedef __attribute__((ext_vector_type(16))) float f32x16;
typedef unsigned int u32;
typedef unsigned long long u64;

#define DEVI __device__ __forceinline__

constexpr int S_ = 2048, D_ = 128, BH_ = 64;
constexpr int KVB = 32, NT = S_ / KVB;                    // 64 kv tiles
constexpr size_t IMG_T   = 16384;                         // per (bh,tile): K-img 8KB + VT-img 8KB
constexpr size_t IMG_ALL = (size_t)BH_ * NT * IMG_T;      // 64 MB
constexpr size_t MOFF    = IMG_ALL;                       // f32 mask region
constexpr size_t WS_NEED = MOFF + (size_t)BH_ * S_ * 4 + 256;

// pack two f32 -> two f16 in one u32 (lo=a, hi=b); emits v_cvt_pkrtz
DEVI u32 pkh(float a, float b){
  u32 la = (u32)__half_as_ushort(__float2half(a));
  u32 lb = (u32)__half_as_ushort(__float2half(b));
  return la | (lb << 16);
}

DEVI f32x16 zero16(){
  f32x16 z;
#pragma unroll
  for (int i = 0; i < 16; ++i) z[i] = 0.0f;
  return z;
}

#define GLOAD16(gsrc, ldst) \
  __builtin_amdgcn_global_load_lds((const __attribute__((address_space(1))) u32*)(gsrc), \
                                   (__attribute__((address_space(3))) u32*)(ldst), 16, 0, 0)
#define GLOAD4(gsrc, ldst) \
  __builtin_amdgcn_global_load_lds((const __attribute__((address_space(1))) u32*)(gsrc), \
                                   (__attribute__((address_space(3))) u32*)(ldst), 4, 0, 0)

// ============================ PRE-PASS ============================
// Builds, per (bh, kv-tile): K fragment image [k8=0..15][row=0..31] 16B chunks
// (chunk = f16 K[row][k8*8 .. +8]) and VT image [v8=0..3][d=0..127] 16B chunks
// (chunk = f16 V[kv0+v8*8+j][d], j=0..7). Plus f32 mask array.
__global__ __launch_bounds__(256)
void sdpa_prepass(const float* __restrict__ Kg, const float* __restrict__ Vg,
                  const int* __restrict__ Mg, char* __restrict__ ws)
{
  __shared__ float T[32][133];   // stride 133: conflict-free column reads
  const int tid = threadIdx.x;
  const int bh = blockIdx.x >> 6, t = blockIdx.x & 63;
  const int kv0 = t * KVB;
  char* img = ws + (size_t)(bh * NT + t) * IMG_T;
  const int r  = tid >> 3;        // 0..31 kv row
  const int c8 = tid & 7;         // 16-float column chunk

  // ---- K: direct convert (coalesced reads, 16B scattered writes -> L2 combines)
  {
    const float* src = Kg + ((size_t)bh * S_ + kv0 + r) * D_ + c8 * 16;
    float4 a = ((const float4*)src)[0];
    float4 b = ((const float4*)src)[1];
    float4 c = ((const float4*)src)[2];
    float4 d = ((const float4*)src)[3];
    uint4 o0, o1;
    o0.x = pkh(a.x,a.y); o0.y = pkh(a.z,a.w); o0.z = pkh(b.x,b.y); o0.w = pkh(b.z,b.w);
    o1.x = pkh(c.x,c.y); o1.y = pkh(c.z,c.w); o1.z = pkh(d.x,d.y); o1.w = pkh(d.z,d.w);
    *(uint4*)(img + (c8*2 + 0)*512 + r*16) = o0;
    *(uint4*)(img + (c8*2 + 1)*512 + r*16) = o1;
  }

  // ---- V: LDS transpose, coalesced writes
  {
    const float* src = Vg + ((size_t)bh * S_ + kv0 + r) * D_ + c8 * 16;
    float4 a = ((const float4*)src)[0];
    float4 b = ((const float4*)src)[1];
    float4 c = ((const float4*)src)[2];
    float4 d = ((const float4*)src)[3];
    float x[16] = {a.x,a.y,a.z,a.w,b.x,b.y,b.z,b.w,c.x,c.y,c.z,c.w,d.x,d.y,d.z,d.w};
#pragma unroll
    for (int i = 0; i < 16; ++i) T[r][c8*16 + i] = x[i];
  }
  __syncthreads();
#pragma unroll
  for (int cc = 0; cc < 2; ++cc){
    int ch = cc*256 + tid;              // 0..511
    int v8 = ch >> 7, d = ch & 127;
    float y[8];
#pragma unroll
    for (int j = 0; j < 8; ++j) y[j] = T[v8*8 + j][d];
    uint4 o;
    o.x = pkh(y[0],y[1]); o.y = pkh(y[2],y[3]); o.z = pkh(y[4],y[5]); o.w = pkh(y[6],y[7]);
    *(uint4*)(img + 8192 + ch*16) = o;
  }

  // ---- mask -> f32 multipliers
  if (t == 0){
    float* Mf = (float*)(ws + MOFF) + (size_t)bh * S_;
    for (int i = tid; i < S_; i += 256)
      Mf[i] = (Mg[(size_t)bh * S_ + i] != 0) ? 1.0f : 0.0f;
  }
}

// ============================ MAIN ============================
// grid=1024 (XCD-swizzled), 256 thr = 4 waves x 32 q rows. Ring of 4 LDS
// buffers, prefetch distance 3, counted vmcnt(10) + raw s_barrier per tile.
__global__ __launch_bounds__(256, 2)
void sdpa_main(const float* __restrict__ Qg, const char* __restrict__ ws,
               float* __restrict__ Og)
{
  __shared__ __align__(16) char Buf[4][16384];
  __shared__ __align__(16) float Mb[4][64];

  const int tid  = threadIdx.x;
  const int lane = tid & 63;
  const int wv   = tid >> 6;
  const int h    = lane >> 5;
  const int r31  = lane & 31;

  const int bi  = blockIdx.x;
  const int xcd = bi & 7, rr2 = bi >> 3;
  const int qb  = rr2 & 15, bhl = rr2 >> 4;
  const int bh  = xcd*8 + bhl;

  const char*  img0 = ws + (size_t)bh * NT * IMG_T;
  const float* Mf   = (const float*)(ws + MOFF) + (size_t)bh * S_;
  const float* Qh   = Qg + (size_t)bh * S_ * D_;
  float*       Oh   = Og + (size_t)bh * S_ * D_;

  const int q0 = qb*128 + wv*32 + r31;

  auto STAGE = [&](int tt, int bufi){
    const char* g = img0 + (size_t)tt * IMG_T;
#pragma unroll
    for (int j = 0; j < 4; ++j){
      int ch = wv*4 + j;
      GLOAD16(g + ch*1024 + lane*16, &Buf[bufi][ch*1024]);
    }
    GLOAD4(Mf + tt*32 + lane, &Mb[bufi][0]);   // all 4 waves: same data, uniform vmcnt
  };

  STAGE(0, 0); STAGE(1, 1); STAGE(2, 2);

  // ---- Q fragments (f16 B-operand: lane holds Q[q0][df*16 + 8h + j]) ----
  short8 qs[8];
#pragma unroll
  for (int df = 0; df < 8; ++df){
    const float* p0 = Qh + (size_t)q0 * D_ + df*16 + h*8;
    float4 a = *(const float4*)(p0);
    float4 b = *(const float4*)(p0 + 4);
    union { u32 u[4]; short8 s; } cv;
    cv.u[0] = pkh(a.x,a.y); cv.u[1] = pkh(a.z,a.w);
    cv.u[2] = pkh(b.x,b.y); cv.u[3] = pkh(b.z,b.w);
    qs[df] = cv.s;
  }
  __syncthreads();   // one full drain in prologue: tiles 0..2 visible everywhere

  f32x16 accO[4];
#pragma unroll
  for (int dn = 0; dn < 4; ++dn) accO[dn] = zero16();
  float mrun = -INFINITY, lrun = 0.0f;

  for (int t = 0; t < NT; ++t){
    const int buf = t & 3;
    if (t){
      asm volatile("s_waitcnt vmcnt(10)" ::: "memory");   // tile t's 5 loads retired
      __builtin_amdgcn_s_barrier();                        // no vmcnt(0) drain!
    }
    { // issue tile t+3 (after barrier: its buffer's last reader is done)
      int tt = (t+3 < NT) ? (t+3) : (NT-1);
      STAGE(tt, (t+3) & 3);
    }

    const char* Kb = Buf[buf];
    const char* Vb = Buf[buf] + 8192;

    // ---- QK^T (swapped): S^T[kv][q] = K * Q^T; frag reads conflict-free ----
    f32x16 sa = zero16();
    __builtin_amdgcn_s_setprio(1);
#pragma unroll
    for (int df = 0; df < 8; ++df){
      short8 kf = *(const short8*)(Kb + ((df*2 + h) << 9) + (r31 << 4));
      sa = __builtin_amdgcn_mfma_f32_32x32x16_f16(kf, qs[df], sa, 0, 0, 0);
    }
    __builtin_amdgcn_s_setprio(0);

    // ---- online softmax (lane owns q col = r31) ----
    float pmax = sa[0];
#pragma unroll
    for (int i = 1; i < 16; ++i) pmax = fmaxf(pmax, sa[i]);
    pmax = fmaxf(pmax, __shfl_xor(pmax, 32, 64));
    if (!__all(pmax - mrun <= 8.0f)){        // T13 defer-rescale
      float mnew = fmaxf(mrun, pmax);
      float sc = __expf(mrun - mnew);
      lrun *= sc;
#pragma unroll
      for (int dn = 0; dn < 4; ++dn)
#pragma unroll
        for (int i = 0; i < 16; ++i) accO[dn][i] *= sc;
      mrun = mnew;
    }
    float psum = 0.0f;
#pragma unroll
    for (int rb = 0; rb < 4; ++rb){
      float4 mv = *(const float4*)&Mb[buf][rb*8 + h*4];
      float mm[4] = {mv.x, mv.y, mv.z, mv.w};
#pragma unroll
      for (int i2 = 0; i2 < 4; ++i2){
        float e = __expf(sa[rb*4+i2] - mrun) * mm[i2];
        sa[rb*4+i2] = e;
        psum += e;
      }
    }
    psum += __shfl_xor(psum, 32, 64);
    lrun += psum;

    // ---- P fragments (C-layout -> B-operand via xor-32 swap) ----
    short8 pf8[2];
#pragma unroll
    for (int kf = 0; kf < 2; ++kf){
      const int o = kf*8;
      u32 w0 = pkh(sa[o+0], sa[o+1]);
      u32 w1 = pkh(sa[o+2], sa[o+3]);
      u32 w2 = pkh(sa[o+4], sa[o+5]);
      u32 w3 = pkh(sa[o+6], sa[o+7]);
      u32 s0 = __shfl_xor(w0, 32, 64);
      u32 s1 = __shfl_xor(w1, 32, 64);
      u32 s2 = __shfl_xor(w2, 32, 64);
      u32 s3 = __shfl_xor(w3, 32, 64);
      union { u32 u[4]; short8 s; } cv;
      cv.u[0] = h ? s2 : w0;
      cv.u[1] = h ? s3 : w1;
      cv.u[2] = h ? w2 : s0;
      cv.u[3] = h ? w3 : s1;
      pf8[kf] = cv.s;
    }

    // ---- PV: O^T[d][q] += V^T * P^T; VT frag reads conflict-free ----
    __builtin_amdgcn_s_setprio(1);
#pragma unroll
    for (int dn = 0; dn < 4; ++dn){
      short8 v0 = *(const short8*)(Vb + (h << 11)       + ((dn*32 + r31) << 4));
      short8 v1 = *(const short8*)(Vb + ((2 + h) << 11) + ((dn*32 + r31) << 4));
      accO[dn] = __builtin_amdgcn_mfma_f32_32x32x16_f16(v0, pf8[0], accO[dn], 0, 0, 0);
      accO[dn] = __builtin_amdgcn_mfma_f32_32x32x16_f16(v1, pf8[1], accO[dn], 0, 0, 0);
    }
    __builtin_amdgcn_s_setprio(0);
  }

  // ---- epilogue ----
  const float inv = 1.0f / lrun;
  float* Orow = Oh + (size_t)q0 * D_;
#pragma unroll
  for (int dn = 0; dn < 4; ++dn){
#pragma unroll
    for (int rb = 0; rb < 4; ++rb){
      float4 o4;
      o4.x = accO[dn][rb*4+0]*inv;
      o4.y = accO[dn][rb*4+1]*inv;
      o4.z = accO[dn][rb*4+2]*inv;
      o4.w = accO[dn][rb*4+3]*inv;
      *(float4*)&Orow[dn*32 + rb*8 + h*4] = o4;
    }
  }
}

// ============================ FALLBACK (round-1 kernel, used if ws too small) ============================
DEVI void sync_lds(){
  asm volatile("s_waitcnt lgkmcnt(0)" ::: "memory");
  __builtin_amdgcn_s_barrier();
}
#define TR_READ(dst, addr, IMM) \
  asm volatile("ds_read_b64_tr_b16 %0, %1 offset:" IMM : "=v"(dst) : "v"(addr))

__global__ __launch_bounds__(256, 2)
void sdpa_fallback(const float* __restrict__ Qg, const float* __restrict__ Kg,
                   const float* __restrict__ Vg, const int* __restrict__ Mg,
                   float* __restrict__ Og)
{
  constexpr int S = 2048, D = 128;
  __shared__ __align__(16) short Klds[64*136];
  __shared__ __align__(16) short Vlds[64*128];
  __shared__ __align__(16) float Mlds[64];

  const int tid  = threadIdx.x;
  const int lane = tid & 63;
  const int wv   = tid >> 6;
  const int h    = lane >> 5;
  const int r31  = lane & 31;
  const int r15  = lane & 15;
  const int b4   = (lane >> 4) & 1;
  const int srow = tid >> 5;
  const int scol = tid & 31;

  const int bh = blockIdx.x >> 4;
  const int qb = blockIdx.x & 15;

  const float* Qh = Qg + (size_t)bh * S * D;
  const float* Kh = Kg + (size_t)bh * S * D;
  const float* Vh = Vg + (size_t)bh * S * D;
  const int*   Mh = Mg + (size_t)bh * S;
  float*       Oh = Og + (size_t)bh * S * D;

  const int q0 = qb*128 + wv*32 + r31;

  short8 qs[8];
#pragma unroll
  for (int df = 0; df < 8; ++df){
    const float* p0 = Qh + (size_t)q0 * D + df*16 + h*8;
    float4 a = *(const float4*)(p0);
    float4 b = *(const float4*)(p0 + 4);
    union { u32 u[4]; short8 s; } cv;
    cv.u[0] = pkh(a.x, a.y); cv.u[1] = pkh(a.z, a.w);
    cv.u[2] = pkh(b.x, b.y); cv.u[3] = pkh(b.z, b.w);
    qs[df] = cv.s;
  }

  float4 kr[8], vr[8];
  int mpre = 1;
#pragma unroll
  for (int p = 0; p < 8; ++p){
    int row = p*8 + srow;
    kr[p] = *(const float4*)&Kh[(size_t)row * D + scol*4];
    vr[p] = *(const float4*)&Vh[(size_t)row * D + scol*4];
  }
  if (tid < 64) mpre = Mh[tid];

  f32x16 accO[4];
#pragma unroll
  for (int dn = 0; dn < 4; ++dn) accO[dn] = zero16();
  float mrun = -INFINITY, lrun = 0.0f;

  const u32 vbase = (u32)(size_t)(&Vlds[0]) + (u32)(h*2048 + b4*128 + r15*8);

  for (int t = 0; t < 32; ++t){
#pragma unroll
    for (int p = 0; p < 8; ++p){
      int row = p*8 + srow;
      u32 k0 = pkh(kr[p].x, kr[p].y), k1 = pkh(kr[p].z, kr[p].w);
      *(u64*)&Klds[row*136 + scol*4] = ((u64)k1 << 32) | k0;
      u32 v0 = pkh(vr[p].x, vr[p].y), v1 = pkh(vr[p].z, vr[p].w);
      int E = (row >> 2)*512 + (scol >> 2)*64 + (row & 3)*16 + (scol & 3)*4;
      *(u64*)&Vlds[E] = ((u64)v1 << 32) | v0;
    }
    if (tid < 64) Mlds[tid] = (mpre != 0) ? 1.0f : 0.0f;

    if (t < 31){
      const int kv0 = (t+1)*64;
#pragma unroll
      for (int p = 0; p < 8; ++p){
        int row = kv0 + p*8 + srow;
        kr[p] = *(const float4*)&Kh[(size_t)row * D + scol*4];
        vr[p] = *(const float4*)&Vh[(size_t)row * D + scol*4];
      }
      if (tid < 64) mpre = Mh[kv0 + tid];
    }

    sync_lds();

    f32x16 sa[2];
    sa[0] = zero16(); sa[1] = zero16();
    __builtin_amdgcn_s_setprio(1);
#pragma unroll
    for (int mf = 0; mf < 2; ++mf){
#pragma unroll
      for (int df = 0; df < 8; ++df){
        short8 kf8 = *(const short8*)&Klds[(mf*32 + r31)*136 + df*16 + h*8];
        sa[mf] = __builtin_amdgcn_mfma_f32_32x32x16_f16(kf8, qs[df], sa[mf], 0, 0, 0);
      }
    }
    __builtin_amdgcn_s_setprio(0);

    float pmax = -3.0e38f;
#pragma unroll
    for (int mf = 0; mf < 2; ++mf)
#pragma unroll
      for (int i = 0; i < 16; ++i) pmax = fmaxf(pmax, sa[mf][i]);
    pmax = fmaxf(pmax, __shfl_xor(pmax, 32, 64));
    const float mnew  = fmaxf(mrun, pmax);
    const float scale = __expf(mrun - mnew);
    float psum = 0.0f;
#pragma unroll
    for (int mf = 0; mf < 2; ++mf){
#pragma unroll
      for (int rb = 0; rb < 4; ++rb){
        float4 mv = *(const float4*)&Mlds[mf*32 + rb*8 + h*4];
        float mva[4] = {mv.x, mv.y, mv.z, mv.w};
#pragma unroll
        for (int i = 0; i < 4; ++i){
          float e = __expf(sa[mf][rb*4 + i] - mnew) * mva[i];
          sa[mf][rb*4 + i] = e;
          psum += e;
        }
      }
    }
    psum += __shfl_xor(psum, 32, 64);
    lrun = lrun * scale + psum;
    mrun = mnew;
#pragma unroll
    for (int dn = 0; dn < 4; ++dn)
#pragma unroll
      for (int i = 0; i < 16; ++i) accO[dn][i] *= scale;

    short8 pf8[4];
#pragma unroll
    for (int kf = 0; kf < 4; ++kf){
      const int mf = kf >> 1, o = (kf & 1)*8;
      u32 w0 = pkh(sa[mf][o+0], sa[mf][o+1]);
      u32 w1 = pkh(sa[mf][o+2], sa[mf][o+3]);
      u32 w2 = pkh(sa[mf][o+4], sa[mf][o+5]);
      u32 w3 = pkh(sa[mf][o+6], sa[mf][o+7]);
      u32 s0 = __shfl_xor(w0, 32, 64);
      u32 s1 = __shfl_xor(w1, 32, 64);
      u32 s2 = __shfl_xor(w2, 32, 64);
      u32 s3 = __shfl_xor(w3, 32, 64);
      union { u32 u[4]; short8 s; } cv;
      cv.u[0] = h ? s2 : w0;
      cv.u[1] = h ? s3 : w1;
      cv.u[2] = h ? w2 : s0;
      cv.u[3] = h ? w3 : s1;
      pf8[kf] = cv.s;
    }

#pragma unroll
    for (int dn = 0; dn < 4; ++dn){
      u32 vdn = vbase + dn*256;
      u64 ta0, ta1, tb0, tb1, tc0, tc1, td0, td1;
      TR_READ(ta0, vdn, "0");     TR_READ(ta1, vdn, "1024");
      TR_READ(tb0, vdn, "4096");  TR_READ(tb1, vdn, "5120");
      TR_READ(tc0, vdn, "8192");  TR_READ(tc1, vdn, "9216");
      TR_READ(td0, vdn, "12288"); TR_READ(td1, vdn, "13312");
      asm volatile("s_waitcnt lgkmcnt(0)" ::: "memory");
      __builtin_amdgcn_sched_barrier(0);
      union { u64 q[2]; short8 s; } fa, fb, fc, fd;
      fa.q[0] = ta0; fa.q[1] = ta1;
      fb.q[0] = tb0; fb.q[1] = tb1;
      fc.q[0] = tc0; fc.q[1] = tc1;
      fd.q[0] = td0; fd.q[1] = td1;
      __builtin_amdgcn_s_setprio(1);
      accO[dn] = __builtin_amdgcn_mfma_f32_32x32x16_f16(fa.s, pf8[0], accO[dn], 0,0,0);
      accO[dn] = __builtin_amdgcn_mfma_f32_32x32x16_f16(fb.s, pf8[1], accO[dn], 0,0,0);
      accO[dn] = __builtin_amdgcn_mfma_f32_32x32x16_f16(fc.s, pf8[2], accO[dn], 0,0,0);
      accO[dn] = __builtin_amdgcn_mfma_f32_32x32x16_f16(fd.s, pf8[3], accO[dn], 0,0,0);
      __builtin_amdgcn_s_setprio(0);
    }

    sync_lds();
  }

  const float inv = 1.0f / lrun;
  float* Orow = Oh + (size_t)q0 * D;
#pragma unroll
  for (int dn = 0; dn < 4; ++dn){
#pragma unroll
    for (int rb = 0; rb < 4; ++rb){
      float4 o4;
      o4.x = accO[dn][rb*4+0]*inv;
      o4.y = accO[dn][rb*4+1]*inv;
      o4.z = accO[dn][rb*4+2]*inv;
      o4.w = accO[dn][rb*4+3]*inv;
      *(float4*)&Orow[dn*32 + rb*8 + h*4] = o4;
    }
  }
}

extern "C" void kernel_launch(void* const* d_in, const int* in_sizes, int n_in,
                              void* d_out, int out_size, void* d_ws, size_t ws_size,
                              hipStream_t stream) {
  const float* q = (const float*)d_in[0];
  const float* k = (const float*)d_in[1];
  const float* v = (const float*)d_in[2];
  const int*   m = (const int*)d_in[3];
  float* out = (float*)d_out;
  if (ws_size >= WS_NEED){
    sdpa_prepass<<<dim3(BH_ * NT), dim3(256), 0, stream>>>(k, v, m, (char*)d_ws);
    sdpa_main<<<dim3(1024), dim3(256), 0, stream>>>(q, (const char*)d_ws, out);
  } else {
    sdpa_fallback<<<dim3(1024), dim3(256), 0, stream>>>(q, k, v, m, out);
  }
}